// Round 14
// baseline (134.639 us; speedup 1.0000x reference)
//
#include <hip/hip_runtime.h>
#include <math.h>

// R14 = R13's proven producer/consumer topology, shrunk to 2 blocks/CU.
// ONE structural change: TC 64->32, so a 64-lane FIR wave covers TWO channel
// groups (lane = 32*sub + t): group g = 2*wave + sub, 14 groups x CPW=6 = 84
// slots >= 81. 7 FIR waves + 2 consumer waves = 576 thr.
// LDS = xs[2][147*32] + ybuf[2][81*33] + wsh + feat ~ 59.2 KB -> 2 blocks/CU:
// the co-resident block hides barriers, prologue and the scan serial chain
// (R13: 120 KB -> 1 block/CU, 37% idle).
// Consumer phase order load->ds_write->scan (R13-proven: pf regs die before
// the scan, no spill). Padded xs (rows 0..31,112..146 zero) -> FIR is pure
// ds_read+fma. 16 chunks of 32 cols (15*32+20=500).

#define NTH      576
#define NFIR     448       // 7 FIR waves
#define CPW      6
#define TC       32
#define XROWS    147       // padded row j = channel j-32; max read = 78+5+63 = 146
#define YSTRIDE  33        // odd stride: conflict-free scan column reads
#define NCHUNK   16        // 15*32 + 20 = 500
#define TAIL     20
#define T_LEN    500
#define C_OUT    81

__global__ __launch_bounds__(NTH)
void snn_ps4_kernel(const float* __restrict__ x,
                    const float* __restrict__ conv_w,
                    const float* __restrict__ conv_b,
                    const float* __restrict__ bn_gamma,
                    const float* __restrict__ bn_beta,
                    const float* __restrict__ bn_mean,
                    const float* __restrict__ bn_var,
                    const float* __restrict__ plif_w,
                    const float* __restrict__ fc_w,
                    const float* __restrict__ fc_b,
                    float* __restrict__ out)
{
    __shared__ float xs[2][XROWS * TC];        // 2 x 18816 B
    __shared__ float ybuf[2][C_OUT * YSTRIDE]; // 2 x 10692 B
    __shared__ float wsh[64];
    __shared__ float feat[C_OUT];              // total ~59.2 KiB

    const int tid = threadIdx.x;
    const int n   = blockIdx.x;
    const float* xn = x + (size_t)n * (80 * T_LEN);

    if (tid < 64) wsh[tid] = conv_w[tid];

    // ---- zero FIR pad rows of BOTH buffers (written once) ----
    for (int i = tid; i < 32 * TC; i += NTH) { xs[0][i] = 0.0f; xs[1][i] = 0.0f; }
    for (int i = tid; i < (XROWS - 112) * TC; i += NTH) {
        xs[0][112 * TC + i] = 0.0f; xs[1][112 * TC + i] = 0.0f;
    }
    // ---- stage chunk 0 -> xs[0] rows 32..111 (80 rows x 8 float4 = 640) ----
    for (int i = tid; i < 640; i += NTH) {
        const int cr = i >> 3, t4 = i & 7;
        float4 v4 = *reinterpret_cast<const float4*>(xn + cr * T_LEN + t4 * 4);
        *reinterpret_cast<float4*>(&xs[0][(cr + 32) * TC + t4 * 4]) = v4;
    }

    // ---- consumer per-lane state (tid 448..575; channel = sid) ----
    float v = 0.0f, cnt = 0.0f, inv_c = 0.0f, bb_c = 0.0f, decay = 0.0f;
    if (tid >= NFIR) {
        const int ch = tid - NFIR;
        decay = 1.0f / (1.0f + expf(-plif_w[0]));
        if (ch < C_OUT) {
            inv_c = bn_gamma[ch] * rsqrtf(bn_var[ch] + 1e-5f);
            bb_c  = conv_b[0] * inv_c + bn_beta[ch] - bn_mean[ch] * inv_c;
        }
    }
    __syncthreads();

    for (int c = 0; c < NCHUNK; ++c) {
        const int b = c & 1;

        if (tid < NFIR) {
            // ========== FIR producers: group g = tid>>5 (0..13) ==========
            const int g   = tid >> 5;          // half-wave group
            const int t   = tid & 31;          // t-column within chunk
            const int co0 = g * CPW;           // 0,6,...,78
            const float* xsb = xs[b];

            float acc[CPW];
            float win[CPW];                    // win[(k+r)%CPW] = padded row co0+k+r
            #pragma unroll
            for (int r = 0; r < CPW; ++r) acc[r] = 0.0f;
            const int base = co0 * TC + t;
            #pragma unroll
            for (int m = 0; m < CPW - 1; ++m) win[m] = xsb[base + m * TC];
            #pragma unroll
            for (int k = 0; k < 64; ++k) {
                win[(k + CPW - 1) % CPW] = xsb[base + (k + CPW - 1) * TC];
                const float wk = wsh[k];       // LDS broadcast
                #pragma unroll
                for (int r = 0; r < CPW; ++r)
                    acc[r] = fmaf(wk, win[(k + r) % CPW], acc[r]);
            }
            #pragma unroll
            for (int r = 0; r < CPW; ++r) {
                const int co = co0 + r;
                if (co < C_OUT) ybuf[b][co * YSTRIDE + t] = acc[r];
            }
        } else {
            // ========== consumers: stage (load->write) then scan ==========
            const int sid = tid - NFIR;        // 0..127

            if (c < NCHUNK - 1) {
                const int t0n = (c + 1) * TC;
                float4 pf[5];
                #pragma unroll
                for (int s = 0; s < 5; ++s) {
                    const int i  = s * 128 + sid;   // 640 items
                    const int cr = i >> 3, t4 = i & 7;
                    int toff = t0n + t4 * 4;
                    if (toff > 496) toff = 496;     // tail dup; cols >=20 unused
                    pf[s] = *reinterpret_cast<const float4*>(xn + cr * T_LEN + toff);
                }
                #pragma unroll
                for (int s = 0; s < 5; ++s) {
                    const int i  = s * 128 + sid;
                    const int cr = i >> 3, t4 = i & 7;
                    *reinterpret_cast<float4*>(&xs[b ^ 1][(cr + 32) * TC + t4 * 4]) = pf[s];
                }
            }

            // PLIF scan of chunk c-1 (32 cols; chunk 15 in epilogue)
            if (c > 0 && sid < C_OUT) {
                const float* yrow = &ybuf[b ^ 1][sid * YSTRIDE];
                #pragma unroll 4
                for (int t = 0; t < TC; ++t) {
                    const float xt = fmaf(yrow[t], inv_c, bb_c);   // BN
                    v = fmaf(xt - v, decay, v);                    // v += (x-v)*decay
                    const bool s = (v >= 1.0f);
                    cnt += s ? 1.0f : 0.0f;
                    v = s ? 0.0f : v;
                }
            }
        }
        __syncthreads();   // single barrier per chunk
    }

    // ---- epilogue: scan chunk 15 (20 cols) from ybuf[1] ----
    if (tid >= NFIR) {
        const int sid = tid - NFIR;
        if (sid < C_OUT) {
            const float* yrow = &ybuf[1][sid * YSTRIDE];
            #pragma unroll 4
            for (int t = 0; t < TAIL; ++t) {
                const float xt = fmaf(yrow[t], inv_c, bb_c);
                v = fmaf(xt - v, decay, v);
                const bool s = (v >= 1.0f);
                cnt += s ? 1.0f : 0.0f;
                v = s ? 0.0f : v;
            }
            feat[sid] = cnt * (1.0f / 500.0f);
        }
    }
    __syncthreads();

    if (tid < 3) {
        float o = fc_b[tid];
        #pragma unroll 3
        for (int cc = 0; cc < C_OUT; ++cc)
            o = fmaf(feat[cc], fc_w[tid * C_OUT + cc], o);
        out[n * 3 + tid] = o;
    }
}

extern "C" void kernel_launch(void* const* d_in, const int* in_sizes, int n_in,
                              void* d_out, int out_size, void* d_ws, size_t ws_size,
                              hipStream_t stream)
{
    const float* x        = (const float*)d_in[0];
    const float* conv_w   = (const float*)d_in[1];
    const float* conv_b   = (const float*)d_in[2];
    const float* bn_gamma = (const float*)d_in[3];
    const float* bn_beta  = (const float*)d_in[4];
    const float* bn_mean  = (const float*)d_in[5];
    const float* bn_var   = (const float*)d_in[6];
    const float* plif_w   = (const float*)d_in[7];
    const float* fc_w     = (const float*)d_in[8];
    const float* fc_b     = (const float*)d_in[9];
    float* out            = (float*)d_out;

    snn_ps4_kernel<<<1024, NTH, 0, stream>>>(
        x, conv_w, conv_b, bn_gamma, bn_beta, bn_mean, bn_var,
        plif_w, fc_w, fc_b, out);
}